// Round 17
// baseline (558.123 us; speedup 1.0000x reference)
//
#include <hip/hip_runtime.h>

#define N_H   5000
#define N_O   15000
#define N_TOT 20000
#define DD    1024
#define E_HH  20000
#define E_OO  40000
#define E_HO  40000
#define E_TOT 100000
#define CAP   128               // padded per-node edge-list capacity (max deg ~20)

typedef unsigned short u16;
typedef unsigned int u32;
typedef __attribute__((ext_vector_type(8))) short short8;
typedef __attribute__((ext_vector_type(4))) float f32x4;
typedef const __attribute__((address_space(1))) u32 gas_u32;
typedef __attribute__((address_space(3))) u32 las_u32;

__device__ __forceinline__ float bf2f(u16 u) {
    union { unsigned int i; float f; } v; v.i = ((unsigned int)u) << 16; return v.f;
}
__device__ __forceinline__ u16 f2bf(float f) {
    union { float f; unsigned int i; } v; v.f = f;
    unsigned int u = v.i;
    return (u16)((u + 0x7FFFu + ((u >> 16) & 1u)) >> 16);
}

// --- fused: cast + edge concat + cursor zero + 5x weight transpose (one launch) -
#define CAST_NB 10000           // (20000*1024)/(256*8)
#define CAT_NB  391             // ceil(100000/256)
#define ZERO_NB 79              // ceil(20000/256)
#define TW_NB   10240           // 32*32*10
struct TW  { const float* W; u16* dT; u16* dB; int ld; };
struct TW5 { TW t[5]; };
__global__ void cast_cat_tw(const float* __restrict__ in, u16* __restrict__ out,
                            const int* __restrict__ shh, const int* __restrict__ dhh,
                            const int* __restrict__ soo, const int* __restrict__ doo,
                            const int* __restrict__ sho, const int* __restrict__ dho,
                            int* __restrict__ src_all, int* __restrict__ dst_all,
                            int* __restrict__ cursor, TW5 p) {
    __shared__ float tile[32][33];
    int b = blockIdx.x;
    if (b < CAST_NB) {
        size_t i = ((size_t)b * 256 + threadIdx.x) * 8;
        float4 a = *(const float4*)(in + i);
        float4 c = *(const float4*)(in + i + 4);
        u16 o[8] = {f2bf(a.x), f2bf(a.y), f2bf(a.z), f2bf(a.w),
                    f2bf(c.x), f2bf(c.y), f2bf(c.z), f2bf(c.w)};
        *(uint4*)(out + i) = *(const uint4*)o;
        return;
    }
    if (b < CAST_NB + CAT_NB) {
        int e = (b - CAST_NB) * 256 + threadIdx.x;
        if (e >= E_TOT) return;
        int s, d;
        if (e < E_HH)              { s = shh[e];               d = dhh[e]; }
        else if (e < E_HH + E_OO)  { s = soo[e - E_HH];        d = doo[e - E_HH]; }
        else                       { s = sho[e - E_HH - E_OO]; d = dho[e - E_HH - E_OO]; }
        src_all[e] = s; dst_all[e] = d;
        return;
    }
    if (b < CAST_NB + CAT_NB + ZERO_NB) {
        int i = (b - CAST_NB - CAT_NB) * 256 + threadIdx.x;
        if (i < N_TOT) cursor[i] = 0;         // consumed by NEXT kernel (stream-ordered)
        return;
    }
    int tb = b - CAST_NB - CAT_NB - ZERO_NB;  // 0..10239
    int z = tb >> 10;                         // 0..9
    int rem = tb & 1023;
    int bk = rem & 31, bn = rem >> 5;
    TW tw = p.t[z >> 1];
    int half = z & 1;
    int tx = threadIdx.x & 31, ty = threadIdx.x >> 5;   // ty 0..7
#pragma unroll
    for (int yy = 0; yy < 4; yy++) {
        int k = half * 1024 + bk * 32 + ty + yy * 8;
        int n = bn * 32 + tx;
        tile[ty + yy * 8][tx] = tw.W[(size_t)k * 1024 + n];
    }
    __syncthreads();
    u16* dst = half ? tw.dB : tw.dT;
#pragma unroll
    for (int yy = 0; yy < 4; yy++) {
        int n = bn * 32 + ty + yy * 8;
        int k = bk * 32 + tx;
        dst[(size_t)n * tw.ld + k] = f2bf(tile[tx][ty + yy * 8]);
    }
}

// ---------------- merged proj GEMM + padded-fill tail range ---------------------
// GEMM blocks [0,3792): 128x128 tile (R5-exact: NO XCD swizzle — R6: swizzle
// thrashed B (6.3MB > 4MB L2)). NOTE (R4): no loop-invariant bias loads here
// (VGPR 80->88, occ -33%, dur +28%).
// Blocks [3792,4183): padded fill — edge_ids[d*CAP+pos], cursor becomes deg.
#define PROJ_NBM_H 40           // ceil(5000/128)
#define PROJ_NBM_O 118          // ceil(15000/128)
#define PROJ_NBN   24           // 3072/128
#define PROJ_GEMM_NB ((PROJ_NBM_H + PROJ_NBM_O) * PROJ_NBN)   // 3792
#define FILL_NB 391
__launch_bounds__(256)
__global__ void gemm_proj(const u16* __restrict__ Ah, const u16* __restrict__ Ao,
                          const u16* __restrict__ Bth, const u16* __restrict__ Bto,
                          u16* __restrict__ Ch, u16* __restrict__ Co,
                          const int* __restrict__ dst_all, int* __restrict__ cursor,
                          int* __restrict__ edge_ids) {
    __shared__ u16 smem[2][128][64];          // staging A | B; reused by epilogue
    int bid = blockIdx.x;
    if (bid >= PROJ_GEMM_NB) {                // padded-fill tail range
        int e = (bid - PROJ_GEMM_NB) * 256 + threadIdx.x;
        if (e < E_TOT) {
            int d = dst_all[e];
            int pos = atomicAdd(&cursor[d], 1);
            if (pos < CAP) edge_ids[(size_t)d * CAP + pos] = e;
        }
        return;
    }
    const u16* A; const u16* Bt; u16* C; int M;
    if (bid < PROJ_NBM_H * PROJ_NBN) { A = Ah; Bt = Bth; C = Ch; M = N_H; }
    else { bid -= PROJ_NBM_H * PROJ_NBN; A = Ao; Bt = Bto; C = Co; M = N_O; }
    int bm = bid / PROJ_NBN, bn = bid % PROJ_NBN;
    int t = threadIdx.x;
    int wave = t >> 6, lane = t & 63;
    int wr = wave >> 1, wc = wave & 1;        // 2x2 wave grid, 64x64 each
    int lm = lane & 15, q = lane >> 4;
    f32x4 acc[4][4] = {};
    int srow = lane >> 3;                     // 0..7 within chunk
    int scol = ((lane & 7) ^ srow) * 8;       // pre-swizzled source chunk

    for (int k0 = 0; k0 < 1024; k0 += 64) {
#pragma unroll
        for (int it = 0; it < 4; it++) {
            int chunk = wave * 4 + it;        // 0..15
            int row = chunk * 8 + srow;
            int gr = bm * 128 + row; if (gr >= M) gr = M - 1;
            __builtin_amdgcn_global_load_lds((gas_u32*)(A + (size_t)gr * 1024 + k0 + scol),
                                             (las_u32*)&smem[0][chunk * 8][0], 16, 0, 0);
            __builtin_amdgcn_global_load_lds((gas_u32*)(Bt + (size_t)(bn * 128 + row) * 1024 + k0 + scol),
                                             (las_u32*)&smem[1][chunk * 8][0], 16, 0, 0);
        }
        __syncthreads();
#pragma unroll
        for (int ks = 0; ks < 64; ks += 32) {
            short8 af[4], bfr[4];
            int pc = (((ks >> 3) + q) ^ (lm & 7)) * 8;
#pragma unroll
            for (int i = 0; i < 4; i++)
                af[i] = *(const short8*)&smem[0][wr * 64 + i * 16 + lm][pc];
#pragma unroll
            for (int j = 0; j < 4; j++)
                bfr[j] = *(const short8*)&smem[1][wc * 64 + j * 16 + lm][pc];
#pragma unroll
            for (int i = 0; i < 4; i++)
#pragma unroll
                for (int j = 0; j < 4; j++)
                    acc[i][j] = __builtin_amdgcn_mfma_f32_16x16x32_bf16(af[i], bfr[j], acc[i][j], 0, 0, 0);
        }
        __syncthreads();   // also guards epilogue LDS reuse (all reads of smem done)
    }
    // acc -> LDS as the full 128x128 bf16 C-tile
    u16* sc = &smem[0][0][0];
#pragma unroll
    for (int i = 0; i < 4; i++)
#pragma unroll
        for (int j = 0; j < 4; j++)
#pragma unroll
            for (int r = 0; r < 4; r++)
                sc[(wr * 64 + i * 16 + q * 4 + r) * 128 + (wc * 64 + j * 16 + lm)] =
                    f2bf(acc[i][j][r]);
    __syncthreads();
    // 256B-contiguous stores: 16 threads cover one 128-col row
#pragma unroll
    for (int it = 0; it < 8; it++) {
        int flat = it * 256 + t;              // 0..2047
        int r = flat >> 4, cs = (flat & 15) * 8;
        int grow = bm * 128 + r;
        if (grow < M)
            *(uint4*)&C[(size_t)grow * 3072 + bn * 128 + cs] = *(const uint4*)&sc[r * 128 + cs];
    }
}

// ---------------- merged node GEMM: out = relu([nf | z] @ W + b), fp32 ----------
// XCD chunked swizzle KEPT (R6 win). K split in 2 halves. LDS-bounce fp32
// epilogue (R9 win: WRITE 110->82MB).
#define NODE_NBM_H 40           // ceil(5000/128)
#define NODE_NBM_O 118          // ceil(15000/128)
#define NODE_NBN   8            // 1024/128
__launch_bounds__(256)
__global__ void gemm_node(const u16* __restrict__ nf_h, const u16* __restrict__ nf_o,
                          const u16* __restrict__ z_h, const u16* __restrict__ z_o,
                          const u16* __restrict__ Bthn, const u16* __restrict__ Bton,
                          const float* __restrict__ b_hn, const float* __restrict__ b_on,
                          float* __restrict__ out_h, float* __restrict__ out_o) {
    __shared__ u16 smem[2][128][64];          // staging A | B; fp32 bounce in epilogue
    int bid = (blockIdx.x & 7) * ((NODE_NBM_H + NODE_NBM_O) * NODE_NBN / 8)
            + (blockIdx.x >> 3);              // XCD chunked swizzle (1264 % 8 == 0)
    const u16 *A0, *A1, *Bt; const float* bias; float* C; int M;
    if (bid < NODE_NBM_H * NODE_NBN) {
        A0 = nf_h; A1 = z_h; Bt = Bthn; bias = b_hn; C = out_h; M = N_H;
    } else {
        bid -= NODE_NBM_H * NODE_NBN;
        A0 = nf_o; A1 = z_o; Bt = Bton; bias = b_on; C = out_o; M = N_O;
    }
    int bm = bid / NODE_NBN, bn = bid % NODE_NBN;
    int t = threadIdx.x;
    int wave = t >> 6, lane = t & 63;
    int wr = wave >> 1, wc = wave & 1;   // 2x2 wave grid, 64x64 each
    int lm = lane & 15, q = lane >> 4;
    f32x4 acc[4][4] = {};
    int srow = lane >> 3;
    int scol = ((lane & 7) ^ srow) * 8;

    for (int half = 0; half < 2; half++) {
        const u16* Asrc = half ? A1 : A0;
        const u16* Bth = Bt + half * 1024;
        for (int k0 = 0; k0 < 1024; k0 += 64) {
#pragma unroll
            for (int it = 0; it < 4; it++) {
                int chunk = wave * 4 + it;
                int row = chunk * 8 + srow;
                int gr = bm * 128 + row; if (gr >= M) gr = M - 1;
                __builtin_amdgcn_global_load_lds((gas_u32*)(Asrc + (size_t)gr * 1024 + k0 + scol),
                                                 (las_u32*)&smem[0][chunk * 8][0], 16, 0, 0);
                __builtin_amdgcn_global_load_lds((gas_u32*)(Bth + (size_t)(bn * 128 + row) * 2048 + k0 + scol),
                                                 (las_u32*)&smem[1][chunk * 8][0], 16, 0, 0);
            }
            __syncthreads();
#pragma unroll
            for (int ks = 0; ks < 64; ks += 32) {
                short8 af[4], bfr[4];
                int pc = (((ks >> 3) + q) ^ (lm & 7)) * 8;
#pragma unroll
                for (int i = 0; i < 4; i++)
                    af[i] = *(const short8*)&smem[0][wr * 64 + i * 16 + lm][pc];
#pragma unroll
                for (int j = 0; j < 4; j++)
                    bfr[j] = *(const short8*)&smem[1][wc * 64 + j * 16 + lm][pc];
#pragma unroll
                for (int i = 0; i < 4; i++)
#pragma unroll
                    for (int j = 0; j < 4; j++)
                        acc[i][j] = __builtin_amdgcn_mfma_f32_16x16x32_bf16(af[i], bfr[j], acc[i][j], 0, 0, 0);
            }
            __syncthreads();
        }
    }
    // fp32 LDS-bounce epilogue: phase p covers tile rows [p*64, p*64+64)
    float* sf = (float*)&smem[0][0][0];       // 32KB = 64 rows x 128 cols fp32
#pragma unroll
    for (int p = 0; p < 2; p++) {
        if (p) __syncthreads();               // WAR vs phase-0 reads
        if (wr == p) {
#pragma unroll
            for (int j = 0; j < 4; j++) {
                int col = wc * 64 + j * 16 + lm;
                float bv = bias[bn * 128 + col];
#pragma unroll
                for (int i = 0; i < 4; i++)
#pragma unroll
                    for (int r = 0; r < 4; r++)
                        sf[(i * 16 + q * 4 + r) * 128 + col] =
                            fmaxf(acc[i][j][r] + bv, 0.0f);
            }
        }
        __syncthreads();
#pragma unroll
        for (int it = 0; it < 8; it++) {
            int c = it * 256 + t;             // 0..2047 16B-chunks
            int rl = c >> 5, k4 = c & 31;
            int grow = bm * 128 + p * 64 + rl;
            if (grow < M)
                *(float4*)&C[(size_t)grow * 1024 + bn * 128 + k4 * 4] =
                    *(const float4*)&sf[rl * 128 + k4 * 4];
        }
    }
}

// ------- fused per-node attention: logits + online softmax + aggregation --------
// R16 base (spill-proof dual-dot + scalar select) + R17: 2-deep issue-early
// pipeline (T14): edge i+1's full gather chain (elist -> src -> u-row + nf-row)
// is issued BEFORE edge i's compute, so its ~600-1200cyc dependent-load latency
// hides under the dot/softmax/aggregate work. Named-variable rotation (rule #20:
// no parity-indexed arrays). h-dst waves skip the dead type-1 dot (wave-uniform).
__launch_bounds__(256, 1)
__global__ void att_soft_z(const int* __restrict__ cursor, const int* __restrict__ edge_ids,
                           const int* __restrict__ src_all,
                           const u16* __restrict__ proj_h, const u16* __restrict__ proj_o,
                           const float* __restrict__ b_hh, const float* __restrict__ b_oo,
                           const float* __restrict__ b_ho,
                           const float* __restrict__ W_att, const float* __restrict__ b_att,
                           const u16* __restrict__ nf, u16* __restrict__ z) {
    int wave = threadIdx.x >> 6, lane = threadIdx.x & 63;
    int node = blockIdx.x * 4 + wave;
    if (node >= N_TOT) return;
    int deg = cursor[node]; if (deg > CAP) deg = CAP;
    const int* elist = edge_ids + (size_t)node * CAP;
    int isH = node < N_H;
    int off = lane * 16;

    float ww[16];
#pragma unroll
    for (int i = 0; i < 16; i++) ww[i] = W_att[off + i];
    const float* b0 = isH ? b_hh : b_oo;
    const u16* v0src = isH ? proj_h + (size_t)node * 3072 + 1024
                           : proj_o + (size_t)(node - N_H) * 3072 + 1024;
    uint4 va0 = *(const uint4*)(v0src + off), va1 = *(const uint4*)(v0src + off + 8);
    const u16* pa0 = (const u16*)&va0; const u16* pa1 = (const u16*)&va1;
    float vf0[16], vf1[16];
#pragma unroll
    for (int j = 0; j < 8; j++) {
        vf0[j]     = bf2f(pa0[j]) + b0[off + j];
        vf0[8 + j] = bf2f(pa1[j]) + b0[off + 8 + j];
    }
#pragma unroll
    for (int j = 0; j < 16; j++) vf1[j] = 0.f;
    if (!isH) {
        const u16* v1src = proj_o + (size_t)(node - N_H) * 3072 + 2048;
        uint4 vb0 = *(const uint4*)(v1src + off), vb1 = *(const uint4*)(v1src + off + 8);
        const u16* pb0 = (const u16*)&vb0; const u16* pb1 = (const u16*)&vb1;
#pragma unroll
        for (int j = 0; j < 8; j++) {
            vf1[j]     = bf2f(pb0[j]) + b_ho[off + j];
            vf1[8 + j] = bf2f(pb1[j]) + b_ho[off + 8 + j];
        }
    }
    float batt = b_att[0];

    float m = -1e30f, ssum = 0.f;
    float av16[16] = {};
    if (deg > 0) {
        // prologue: load edge 0
        int eid = elist[0];
        int s = src_all[eid];
        int typ1 = 0;
        const u16* u;
        if (eid < E_HH)             { u = proj_h + (size_t)s * 3072; }
        else if (eid < E_HH + E_OO) { u = proj_o + (size_t)(s - N_H) * 3072; }
        else                        { u = proj_h + (size_t)s * 3072 + 2048; typ1 = 1; }
        uint4 u0 = *(const uint4*)(u + off), u1 = *(const uint4*)(u + off + 8);
        const u16* nr = nf + (size_t)s * DD + off;
        uint4 p0 = *(const uint4*)nr, p1 = *(const uint4*)(nr + 8);
        for (int i = 0; i < deg; i++) {
            // issue-early: next edge's gathers before current compute
            int inx = (i + 1 < deg) ? i + 1 : i;    // clamped (re-load last: L1 hit)
            int eidn = elist[inx];
            int sn = src_all[eidn];
            int ntyp1 = 0;
            const u16* un;
            if (eidn < E_HH)             { un = proj_h + (size_t)sn * 3072; }
            else if (eidn < E_HH + E_OO) { un = proj_o + (size_t)(sn - N_H) * 3072; }
            else                         { un = proj_h + (size_t)sn * 3072 + 2048; ntyp1 = 1; }
            uint4 nu0 = *(const uint4*)(un + off), nu1 = *(const uint4*)(un + off + 8);
            const u16* nrn = nf + (size_t)sn * DD + off;
            uint4 np0 = *(const uint4*)nrn, np1 = *(const uint4*)(nrn + 8);
            // current compute
            const u16* pu0 = (const u16*)&u0; const u16* pu1 = (const u16*)&u1;
            const u16* pp0 = (const u16*)&p0; const u16* pp1 = (const u16*)&p1;
            float acc0 = 0.f, acc1 = 0.f;
#pragma unroll
            for (int j = 0; j < 8; j++) {
                float uv = bf2f(pu0[j]);
                acc0 += fmaxf(uv + vf0[j], 0.f) * ww[j];
            }
#pragma unroll
            for (int j = 0; j < 8; j++) {
                float uv = bf2f(pu1[j]);
                acc0 += fmaxf(uv + vf0[8 + j], 0.f) * ww[8 + j];
            }
            if (!isH) {                           // h-dst edges are all type-0
#pragma unroll
                for (int j = 0; j < 8; j++) {
                    float uv = bf2f(pu0[j]);
                    acc1 += fmaxf(uv + vf1[j], 0.f) * ww[j];
                }
#pragma unroll
                for (int j = 0; j < 8; j++) {
                    float uv = bf2f(pu1[j]);
                    acc1 += fmaxf(uv + vf1[8 + j], 0.f) * ww[8 + j];
                }
            }
            float acc = typ1 ? acc1 : acc0;       // scalar select (v_cndmask)
#pragma unroll
            for (int o = 32; o > 0; o >>= 1) acc += __shfl_xor(acc, o);
            float l = acc + batt;
            float pw;
            if (l > m) {                          // wave-uniform branch
                float sc = __expf(m - l);         // first iter: exp(-1e30)=0 zeroes
                ssum *= sc;
#pragma unroll
                for (int j = 0; j < 16; j++) av16[j] *= sc;
                m = l; pw = 1.0f;
            } else {
                pw = __expf(l - m);
            }
            ssum += pw;
#pragma unroll
            for (int j = 0; j < 8; j++) av16[j]     += pw * bf2f(pp0[j]);
#pragma unroll
            for (int j = 0; j < 8; j++) av16[8 + j] += pw * bf2f(pp1[j]);
            // rotate pipeline registers
            u0 = nu0; u1 = nu1; p0 = np0; p1 = np1; typ1 = ntyp1;
        }
    }
    float inv = (ssum > 0.f) ? 1.0f / ssum : 0.f;
    u16 ov[16];
#pragma unroll
    for (int j = 0; j < 16; j++) ov[j] = f2bf(av16[j] * inv);
    const uint4* po = (const uint4*)ov;
    *(uint4*)(z + (size_t)node * DD + off)     = po[0];
    *(uint4*)(z + (size_t)node * DD + off + 8) = po[1];
}

// ---------------- launch --------------------------------------------------------
extern "C" void kernel_launch(void* const* d_in, const int* in_sizes, int n_in,
                              void* d_out, int out_size, void* d_ws, size_t ws_size,
                              hipStream_t stream) {
    const float* nf   = (const float*)d_in[0];
    const int* shh    = (const int*)d_in[1];
    const int* dhh    = (const int*)d_in[2];
    const int* soo    = (const int*)d_in[3];
    const int* doo    = (const int*)d_in[4];
    const int* sho    = (const int*)d_in[5];
    const int* dho    = (const int*)d_in[6];
    const float* W_hh = (const float*)d_in[7];
    const float* b_hh = (const float*)d_in[8];
    const float* W_oo = (const float*)d_in[9];
    const float* b_oo = (const float*)d_in[10];
    const float* W_ho = (const float*)d_in[11];
    const float* b_ho = (const float*)d_in[12];
    const float* W_att= (const float*)d_in[13];
    const float* b_att= (const float*)d_in[14];
    const float* W_hn = (const float*)d_in[15];
    const float* b_hn = (const float*)d_in[16];
    const float* W_on = (const float*)d_in[17];
    const float* b_on = (const float*)d_in[18];
    float* out = (float*)d_out;

    char* ws = (char*)d_ws;
    size_t off = 0;
    auto alloc = [&](size_t bytes) -> char* {
        char* p = ws + off;
        off += (bytes + 255) & ~(size_t)255;
        return p;
    };
    u16* nf_bf = (u16*)alloc((size_t)N_TOT * DD * 2);          // 41.9 MB
    u16* Bt_h  = (u16*)alloc((size_t)3072 * 1024 * 2);         // 6.3 MB
    u16* Bt_o  = (u16*)alloc((size_t)3072 * 1024 * 2);
    u16* Bt_hn = (u16*)alloc((size_t)1024 * 2048 * 2);         // 4.2 MB
    u16* Bt_on = (u16*)alloc((size_t)1024 * 2048 * 2);
    u16* proj_h = (u16*)alloc((size_t)N_H * 3072 * 2);         // 30.7 MB
    u16* proj_o = (u16*)alloc((size_t)N_O * 3072 * 2);         // 92.2 MB
    // z DEDICATED: att_soft_z reads proj (u/v rows) while writing z.
    u16* z_bf  = (u16*)alloc((size_t)N_TOT * DD * 2);          // 41.9 MB
    int* src_all  = (int*)alloc(E_TOT * 4);
    int* dst_all  = (int*)alloc(E_TOT * 4);
    int* deg      = (int*)alloc(2 * N_TOT * 4);
    int* cursor   = deg + N_TOT;
    int* edge_ids = (int*)alloc((size_t)N_TOT * CAP * 4);      // 10.2 MB padded
    (void)ws_size; (void)in_sizes; (void)n_in; (void)out_size;

    TW5 tws;
    tws.t[0] = {W_hh, Bt_h,                       Bt_h + (size_t)1024 * 1024, 1024};
    tws.t[1] = {W_oo, Bt_o,                       Bt_o + (size_t)1024 * 1024, 1024};
    tws.t[2] = {W_ho, Bt_h + (size_t)2048 * 1024, Bt_o + (size_t)2048 * 1024, 1024};
    tws.t[3] = {W_hn, Bt_hn,                      Bt_hn + 1024,               2048};
    tws.t[4] = {W_on, Bt_on,                      Bt_on + 1024,               2048};
    // 1. fused cast + edge concat + cursor zero + weight transposes
    cast_cat_tw<<<CAST_NB + CAT_NB + ZERO_NB + TW_NB, 256, 0, stream>>>(
        nf, nf_bf, shh, dhh, soo, doo, sho, dho, src_all, dst_all, cursor, tws);

    const u16* nf_bf_o = nf_bf + (size_t)N_H * DD;
    // 2. merged projections (R5-exact structure) + padded-fill tail range
    gemm_proj<<<PROJ_GEMM_NB + FILL_NB, 256, 0, stream>>>(
        nf_bf, nf_bf_o, Bt_h, Bt_o, proj_h, proj_o, dst_all, cursor, edge_ids);

    // 3. fused attention logits + online softmax + aggregation (wave-per-node)
    att_soft_z<<<N_TOT / 4, 256, 0, stream>>>(cursor, edge_ids, src_all,
                                              proj_h, proj_o, b_hh, b_oo, b_ho,
                                              W_att, b_att, nf_bf, z_bf);

    // 4. merged node apply: out = relu([nf | z] @ W + b) fp32 (XCD swizzle kept)
    gemm_node<<<(NODE_NBM_H + NODE_NBM_O) * NODE_NBN, 256, 0, stream>>>(
        nf_bf, nf_bf_o, z_bf, z_bf + (size_t)N_H * DD, Bt_hn, Bt_on,
        b_hn, b_on, out, out + (size_t)N_H * DD);
}

// Round 18
// 544.300 us; speedup vs baseline: 1.0254x; 1.0254x over previous
//
#include <hip/hip_runtime.h>

#define N_H   5000
#define N_O   15000
#define N_TOT 20000
#define DD    1024
#define E_HH  20000
#define E_OO  40000
#define E_HO  40000
#define E_TOT 100000
#define CAP   128               // padded per-node edge-list capacity (max deg ~20)

typedef unsigned short u16;
typedef unsigned int u32;
typedef __attribute__((ext_vector_type(8))) short short8;
typedef __attribute__((ext_vector_type(4))) float f32x4;
typedef const __attribute__((address_space(1))) u32 gas_u32;
typedef __attribute__((address_space(3))) u32 las_u32;

__device__ __forceinline__ float bf2f(u16 u) {
    union { unsigned int i; float f; } v; v.i = ((unsigned int)u) << 16; return v.f;
}
__device__ __forceinline__ u16 f2bf(float f) {
    union { float f; unsigned int i; } v; v.f = f;
    unsigned int u = v.i;
    return (u16)((u + 0x7FFFu + ((u >> 16) & 1u)) >> 16);
}

// --- fused: cast + edge concat + cursor zero + 5x weight transpose (one launch) -
// R17 lesson: do NOT hand-pipeline the attention gather loop (compiler already
// hoists next-iter loads; manual 2-deep rotation cost +32 VGPR and +10.8us).
#define CAST_NB 10000           // (20000*1024)/(256*8)
#define CAT_NB  391             // ceil(100000/256)
#define ZERO_NB 79              // ceil(20000/256)
#define TW_NB   10240           // 32*32*10
struct TW  { const float* W; u16* dT; u16* dB; int ld; };
struct TW5 { TW t[5]; };
__global__ void cast_cat_tw(const float* __restrict__ in, u16* __restrict__ out,
                            const int* __restrict__ shh, const int* __restrict__ dhh,
                            const int* __restrict__ soo, const int* __restrict__ doo,
                            const int* __restrict__ sho, const int* __restrict__ dho,
                            int* __restrict__ src_all, int* __restrict__ dst_all,
                            int* __restrict__ cursor, TW5 p) {
    __shared__ float tile[32][33];
    int b = blockIdx.x;
    if (b < CAST_NB) {
        size_t i = ((size_t)b * 256 + threadIdx.x) * 8;
        float4 a = *(const float4*)(in + i);
        float4 c = *(const float4*)(in + i + 4);
        u16 o[8] = {f2bf(a.x), f2bf(a.y), f2bf(a.z), f2bf(a.w),
                    f2bf(c.x), f2bf(c.y), f2bf(c.z), f2bf(c.w)};
        *(uint4*)(out + i) = *(const uint4*)o;
        return;
    }
    if (b < CAST_NB + CAT_NB) {
        int e = (b - CAST_NB) * 256 + threadIdx.x;
        if (e >= E_TOT) return;
        int s, d;
        if (e < E_HH)              { s = shh[e];               d = dhh[e]; }
        else if (e < E_HH + E_OO)  { s = soo[e - E_HH];        d = doo[e - E_HH]; }
        else                       { s = sho[e - E_HH - E_OO]; d = dho[e - E_HH - E_OO]; }
        src_all[e] = s; dst_all[e] = d;
        return;
    }
    if (b < CAST_NB + CAT_NB + ZERO_NB) {
        int i = (b - CAST_NB - CAT_NB) * 256 + threadIdx.x;
        if (i < N_TOT) cursor[i] = 0;         // consumed by NEXT kernel (stream-ordered)
        return;
    }
    int tb = b - CAST_NB - CAT_NB - ZERO_NB;  // 0..10239
    int z = tb >> 10;                         // 0..9
    int rem = tb & 1023;
    int bk = rem & 31, bn = rem >> 5;
    TW tw = p.t[z >> 1];
    int half = z & 1;
    int tx = threadIdx.x & 31, ty = threadIdx.x >> 5;   // ty 0..7
#pragma unroll
    for (int yy = 0; yy < 4; yy++) {
        int k = half * 1024 + bk * 32 + ty + yy * 8;
        int n = bn * 32 + tx;
        tile[ty + yy * 8][tx] = tw.W[(size_t)k * 1024 + n];
    }
    __syncthreads();
    u16* dst = half ? tw.dB : tw.dT;
#pragma unroll
    for (int yy = 0; yy < 4; yy++) {
        int n = bn * 32 + ty + yy * 8;
        int k = bk * 32 + tx;
        dst[(size_t)n * tw.ld + k] = f2bf(tile[tx][ty + yy * 8]);
    }
}

// ---------------- merged proj GEMM + padded-fill tail range ---------------------
// GEMM blocks [0,3792): 128x128 tile (R5-exact: NO XCD swizzle — R6: swizzle
// thrashed B (6.3MB > 4MB L2)). NOTE (R4): no loop-invariant bias loads here
// (VGPR 80->88, occ -33%, dur +28%).
// Blocks [3792,4183): padded fill — edge_ids[d*CAP+pos], cursor becomes deg.
#define PROJ_NBM_H 40           // ceil(5000/128)
#define PROJ_NBM_O 118          // ceil(15000/128)
#define PROJ_NBN   24           // 3072/128
#define PROJ_GEMM_NB ((PROJ_NBM_H + PROJ_NBM_O) * PROJ_NBN)   // 3792
#define FILL_NB 391
__launch_bounds__(256)
__global__ void gemm_proj(const u16* __restrict__ Ah, const u16* __restrict__ Ao,
                          const u16* __restrict__ Bth, const u16* __restrict__ Bto,
                          u16* __restrict__ Ch, u16* __restrict__ Co,
                          const int* __restrict__ dst_all, int* __restrict__ cursor,
                          int* __restrict__ edge_ids) {
    __shared__ u16 smem[2][128][64];          // staging A | B; reused by epilogue
    int bid = blockIdx.x;
    if (bid >= PROJ_GEMM_NB) {                // padded-fill tail range
        int e = (bid - PROJ_GEMM_NB) * 256 + threadIdx.x;
        if (e < E_TOT) {
            int d = dst_all[e];
            int pos = atomicAdd(&cursor[d], 1);
            if (pos < CAP) edge_ids[(size_t)d * CAP + pos] = e;
        }
        return;
    }
    const u16* A; const u16* Bt; u16* C; int M;
    if (bid < PROJ_NBM_H * PROJ_NBN) { A = Ah; Bt = Bth; C = Ch; M = N_H; }
    else { bid -= PROJ_NBM_H * PROJ_NBN; A = Ao; Bt = Bto; C = Co; M = N_O; }
    int bm = bid / PROJ_NBN, bn = bid % PROJ_NBN;
    int t = threadIdx.x;
    int wave = t >> 6, lane = t & 63;
    int wr = wave >> 1, wc = wave & 1;        // 2x2 wave grid, 64x64 each
    int lm = lane & 15, q = lane >> 4;
    f32x4 acc[4][4] = {};
    int srow = lane >> 3;                     // 0..7 within chunk
    int scol = ((lane & 7) ^ srow) * 8;       // pre-swizzled source chunk

    for (int k0 = 0; k0 < 1024; k0 += 64) {
#pragma unroll
        for (int it = 0; it < 4; it++) {
            int chunk = wave * 4 + it;        // 0..15
            int row = chunk * 8 + srow;
            int gr = bm * 128 + row; if (gr >= M) gr = M - 1;
            __builtin_amdgcn_global_load_lds((gas_u32*)(A + (size_t)gr * 1024 + k0 + scol),
                                             (las_u32*)&smem[0][chunk * 8][0], 16, 0, 0);
            __builtin_amdgcn_global_load_lds((gas_u32*)(Bt + (size_t)(bn * 128 + row) * 1024 + k0 + scol),
                                             (las_u32*)&smem[1][chunk * 8][0], 16, 0, 0);
        }
        __syncthreads();
#pragma unroll
        for (int ks = 0; ks < 64; ks += 32) {
            short8 af[4], bfr[4];
            int pc = (((ks >> 3) + q) ^ (lm & 7)) * 8;
#pragma unroll
            for (int i = 0; i < 4; i++)
                af[i] = *(const short8*)&smem[0][wr * 64 + i * 16 + lm][pc];
#pragma unroll
            for (int j = 0; j < 4; j++)
                bfr[j] = *(const short8*)&smem[1][wc * 64 + j * 16 + lm][pc];
#pragma unroll
            for (int i = 0; i < 4; i++)
#pragma unroll
                for (int j = 0; j < 4; j++)
                    acc[i][j] = __builtin_amdgcn_mfma_f32_16x16x32_bf16(af[i], bfr[j], acc[i][j], 0, 0, 0);
        }
        __syncthreads();   // also guards epilogue LDS reuse (all reads of smem done)
    }
    // acc -> LDS as the full 128x128 bf16 C-tile
    u16* sc = &smem[0][0][0];
#pragma unroll
    for (int i = 0; i < 4; i++)
#pragma unroll
        for (int j = 0; j < 4; j++)
#pragma unroll
            for (int r = 0; r < 4; r++)
                sc[(wr * 64 + i * 16 + q * 4 + r) * 128 + (wc * 64 + j * 16 + lm)] =
                    f2bf(acc[i][j][r]);
    __syncthreads();
    // 256B-contiguous stores: 16 threads cover one 128-col row
#pragma unroll
    for (int it = 0; it < 8; it++) {
        int flat = it * 256 + t;              // 0..2047
        int r = flat >> 4, cs = (flat & 15) * 8;
        int grow = bm * 128 + r;
        if (grow < M)
            *(uint4*)&C[(size_t)grow * 3072 + bn * 128 + cs] = *(const uint4*)&sc[r * 128 + cs];
    }
}

// ---------------- merged node GEMM: out = relu([nf | z] @ W + b), fp32 ----------
// XCD chunked swizzle KEPT (R6 win). K split in 2 halves. LDS-bounce fp32
// epilogue (R9 win: WRITE 110->82MB).
#define NODE_NBM_H 40           // ceil(5000/128)
#define NODE_NBM_O 118          // ceil(15000/128)
#define NODE_NBN   8            // 1024/128
__launch_bounds__(256)
__global__ void gemm_node(const u16* __restrict__ nf_h, const u16* __restrict__ nf_o,
                          const u16* __restrict__ z_h, const u16* __restrict__ z_o,
                          const u16* __restrict__ Bthn, const u16* __restrict__ Bton,
                          const float* __restrict__ b_hn, const float* __restrict__ b_on,
                          float* __restrict__ out_h, float* __restrict__ out_o) {
    __shared__ u16 smem[2][128][64];          // staging A | B; fp32 bounce in epilogue
    int bid = (blockIdx.x & 7) * ((NODE_NBM_H + NODE_NBM_O) * NODE_NBN / 8)
            + (blockIdx.x >> 3);              // XCD chunked swizzle (1264 % 8 == 0)
    const u16 *A0, *A1, *Bt; const float* bias; float* C; int M;
    if (bid < NODE_NBM_H * NODE_NBN) {
        A0 = nf_h; A1 = z_h; Bt = Bthn; bias = b_hn; C = out_h; M = N_H;
    } else {
        bid -= NODE_NBM_H * NODE_NBN;
        A0 = nf_o; A1 = z_o; Bt = Bton; bias = b_on; C = out_o; M = N_O;
    }
    int bm = bid / NODE_NBN, bn = bid % NODE_NBN;
    int t = threadIdx.x;
    int wave = t >> 6, lane = t & 63;
    int wr = wave >> 1, wc = wave & 1;   // 2x2 wave grid, 64x64 each
    int lm = lane & 15, q = lane >> 4;
    f32x4 acc[4][4] = {};
    int srow = lane >> 3;
    int scol = ((lane & 7) ^ srow) * 8;

    for (int half = 0; half < 2; half++) {
        const u16* Asrc = half ? A1 : A0;
        const u16* Bth = Bt + half * 1024;
        for (int k0 = 0; k0 < 1024; k0 += 64) {
#pragma unroll
            for (int it = 0; it < 4; it++) {
                int chunk = wave * 4 + it;
                int row = chunk * 8 + srow;
                int gr = bm * 128 + row; if (gr >= M) gr = M - 1;
                __builtin_amdgcn_global_load_lds((gas_u32*)(Asrc + (size_t)gr * 1024 + k0 + scol),
                                                 (las_u32*)&smem[0][chunk * 8][0], 16, 0, 0);
                __builtin_amdgcn_global_load_lds((gas_u32*)(Bth + (size_t)(bn * 128 + row) * 2048 + k0 + scol),
                                                 (las_u32*)&smem[1][chunk * 8][0], 16, 0, 0);
            }
            __syncthreads();
#pragma unroll
            for (int ks = 0; ks < 64; ks += 32) {
                short8 af[4], bfr[4];
                int pc = (((ks >> 3) + q) ^ (lm & 7)) * 8;
#pragma unroll
                for (int i = 0; i < 4; i++)
                    af[i] = *(const short8*)&smem[0][wr * 64 + i * 16 + lm][pc];
#pragma unroll
                for (int j = 0; j < 4; j++)
                    bfr[j] = *(const short8*)&smem[1][wc * 64 + j * 16 + lm][pc];
#pragma unroll
                for (int i = 0; i < 4; i++)
#pragma unroll
                    for (int j = 0; j < 4; j++)
                        acc[i][j] = __builtin_amdgcn_mfma_f32_16x16x32_bf16(af[i], bfr[j], acc[i][j], 0, 0, 0);
            }
            __syncthreads();
        }
    }
    // fp32 LDS-bounce epilogue: phase p covers tile rows [p*64, p*64+64)
    float* sf = (float*)&smem[0][0][0];       // 32KB = 64 rows x 128 cols fp32
#pragma unroll
    for (int p = 0; p < 2; p++) {
        if (p) __syncthreads();               // WAR vs phase-0 reads
        if (wr == p) {
#pragma unroll
            for (int j = 0; j < 4; j++) {
                int col = wc * 64 + j * 16 + lm;
                float bv = bias[bn * 128 + col];
#pragma unroll
                for (int i = 0; i < 4; i++)
#pragma unroll
                    for (int r = 0; r < 4; r++)
                        sf[(i * 16 + q * 4 + r) * 128 + col] =
                            fmaxf(acc[i][j][r] + bv, 0.0f);
            }
        }
        __syncthreads();
#pragma unroll
        for (int it = 0; it < 8; it++) {
            int c = it * 256 + t;             // 0..2047 16B-chunks
            int rl = c >> 5, k4 = c & 31;
            int grow = bm * 128 + p * 64 + rl;
            if (grow < M)
                *(float4*)&C[(size_t)grow * 1024 + bn * 128 + k4 * 4] =
                    *(const float4*)&sf[rl * 128 + k4 * 4];
        }
    }
}

// ------- fused per-node attention: logits + online softmax + aggregation --------
// R16-exact (measured best). Spill-proof codegen: compute BOTH dots with
// statically-indexed arrays, select the SCALAR result (one v_cndmask) — a
// runtime select between ARRAYS demotes them to scratch (R14: VGPR 48, +158MB
// spill WRITE, occ 1.9%). No manual gather pipelining (R17: +10.8us — the
// compiler already hoists next-iter loads; hand rotation only adds VGPR).
__launch_bounds__(256, 1)
__global__ void att_soft_z(const int* __restrict__ cursor, const int* __restrict__ edge_ids,
                           const int* __restrict__ src_all,
                           const u16* __restrict__ proj_h, const u16* __restrict__ proj_o,
                           const float* __restrict__ b_hh, const float* __restrict__ b_oo,
                           const float* __restrict__ b_ho,
                           const float* __restrict__ W_att, const float* __restrict__ b_att,
                           const u16* __restrict__ nf, u16* __restrict__ z) {
    int wave = threadIdx.x >> 6, lane = threadIdx.x & 63;
    int node = blockIdx.x * 4 + wave;
    if (node >= N_TOT) return;
    int deg = cursor[node]; if (deg > CAP) deg = CAP;
    const int* elist = edge_ids + (size_t)node * CAP;
    int isH = node < N_H;
    int off = lane * 16;

    float ww[16];
#pragma unroll
    for (int i = 0; i < 16; i++) ww[i] = W_att[off + i];
    // vf0 = v_row(+bias) for type-0 edges (hh for h-dst, oo for o-dst);
    // vf1 = v_row(+bias) for ho edges (o-dst only; zeros for h-dst).
    const float* b0 = isH ? b_hh : b_oo;
    const u16* v0src = isH ? proj_h + (size_t)node * 3072 + 1024
                           : proj_o + (size_t)(node - N_H) * 3072 + 1024;
    uint4 va0 = *(const uint4*)(v0src + off), va1 = *(const uint4*)(v0src + off + 8);
    const u16* pa0 = (const u16*)&va0; const u16* pa1 = (const u16*)&va1;
    float vf0[16], vf1[16];
#pragma unroll
    for (int j = 0; j < 8; j++) {
        vf0[j]     = bf2f(pa0[j]) + b0[off + j];
        vf0[8 + j] = bf2f(pa1[j]) + b0[off + 8 + j];
    }
#pragma unroll
    for (int j = 0; j < 16; j++) vf1[j] = 0.f;
    if (!isH) {
        const u16* v1src = proj_o + (size_t)(node - N_H) * 3072 + 2048;
        uint4 vb0 = *(const uint4*)(v1src + off), vb1 = *(const uint4*)(v1src + off + 8);
        const u16* pb0 = (const u16*)&vb0; const u16* pb1 = (const u16*)&vb1;
#pragma unroll
        for (int j = 0; j < 8; j++) {
            vf1[j]     = bf2f(pb0[j]) + b_ho[off + j];
            vf1[8 + j] = bf2f(pb1[j]) + b_ho[off + 8 + j];
        }
    }
    float batt = b_att[0];

    float m = -1e30f, ssum = 0.f;
    float av16[16] = {};
    for (int i = 0; i < deg; i++) {
        int eid = elist[i];                   // wave-uniform broadcast
        int s = src_all[eid];
        const u16* u; int typ1 = 0;
        if (eid < E_HH)             { u = proj_h + (size_t)s * 3072; }
        else if (eid < E_HH + E_OO) { u = proj_o + (size_t)(s - N_H) * 3072; }
        else                        { u = proj_h + (size_t)s * 3072 + 2048; typ1 = 1; }
        uint4 u0 = *(const uint4*)(u + off), u1 = *(const uint4*)(u + off + 8);
        const u16* nrow = nf + (size_t)s * DD + off;          // independent gather
        uint4 p0 = *(const uint4*)nrow, p1 = *(const uint4*)(nrow + 8);
        const u16* pu0 = (const u16*)&u0; const u16* pu1 = (const u16*)&u1;
        const u16* pp0 = (const u16*)&p0; const u16* pp1 = (const u16*)&p1;
        float acc0 = 0.f, acc1 = 0.f;         // both dots; static indexing only
#pragma unroll
        for (int j = 0; j < 8; j++) {
            float uv = bf2f(pu0[j]);
            acc0 += fmaxf(uv + vf0[j], 0.f) * ww[j];
            acc1 += fmaxf(uv + vf1[j], 0.f) * ww[j];
        }
#pragma unroll
        for (int j = 0; j < 8; j++) {
            float uv = bf2f(pu1[j]);
            acc0 += fmaxf(uv + vf0[8 + j], 0.f) * ww[8 + j];
            acc1 += fmaxf(uv + vf1[8 + j], 0.f) * ww[8 + j];
        }
        float acc = typ1 ? acc1 : acc0;       // scalar select (v_cndmask)
#pragma unroll
        for (int o = 32; o > 0; o >>= 1) acc += __shfl_xor(acc, o);   // all lanes
        float l = acc + batt;
        float pw;
        if (l > m) {                          // wave-uniform branch
            float sc = __expf(m - l);         // first iter: exp(-1e30) = 0 -> zeroes
            ssum *= sc;
#pragma unroll
            for (int j = 0; j < 16; j++) av16[j] *= sc;
            m = l; pw = 1.0f;
        } else {
            pw = __expf(l - m);
        }
        ssum += pw;
#pragma unroll
        for (int j = 0; j < 8; j++) av16[j]     += pw * bf2f(pp0[j]);
#pragma unroll
        for (int j = 0; j < 8; j++) av16[8 + j] += pw * bf2f(pp1[j]);
    }
    float inv = (ssum > 0.f) ? 1.0f / ssum : 0.f;
    u16 ov[16];
#pragma unroll
    for (int j = 0; j < 16; j++) ov[j] = f2bf(av16[j] * inv);
    const uint4* po = (const uint4*)ov;
    *(uint4*)(z + (size_t)node * DD + off)     = po[0];
    *(uint4*)(z + (size_t)node * DD + off + 8) = po[1];
}

// ---------------- launch --------------------------------------------------------
extern "C" void kernel_launch(void* const* d_in, const int* in_sizes, int n_in,
                              void* d_out, int out_size, void* d_ws, size_t ws_size,
                              hipStream_t stream) {
    const float* nf   = (const float*)d_in[0];
    const int* shh    = (const int*)d_in[1];
    const int* dhh    = (const int*)d_in[2];
    const int* soo    = (const int*)d_in[3];
    const int* doo    = (const int*)d_in[4];
    const int* sho    = (const int*)d_in[5];
    const int* dho    = (const int*)d_in[6];
    const float* W_hh = (const float*)d_in[7];
    const float* b_hh = (const float*)d_in[8];
    const float* W_oo = (const float*)d_in[9];
    const float* b_oo = (const float*)d_in[10];
    const float* W_ho = (const float*)d_in[11];
    const float* b_ho = (const float*)d_in[12];
    const float* W_att= (const float*)d_in[13];
    const float* b_att= (const float*)d_in[14];
    const float* W_hn = (const float*)d_in[15];
    const float* b_hn = (const float*)d_in[16];
    const float* W_on = (const float*)d_in[17];
    const float* b_on = (const float*)d_in[18];
    float* out = (float*)d_out;

    char* ws = (char*)d_ws;
    size_t off = 0;
    auto alloc = [&](size_t bytes) -> char* {
        char* p = ws + off;
        off += (bytes + 255) & ~(size_t)255;
        return p;
    };
    u16* nf_bf = (u16*)alloc((size_t)N_TOT * DD * 2);          // 41.9 MB
    u16* Bt_h  = (u16*)alloc((size_t)3072 * 1024 * 2);         // 6.3 MB
    u16* Bt_o  = (u16*)alloc((size_t)3072 * 1024 * 2);
    u16* Bt_hn = (u16*)alloc((size_t)1024 * 2048 * 2);         // 4.2 MB
    u16* Bt_on = (u16*)alloc((size_t)1024 * 2048 * 2);
    u16* proj_h = (u16*)alloc((size_t)N_H * 3072 * 2);         // 30.7 MB
    u16* proj_o = (u16*)alloc((size_t)N_O * 3072 * 2);         // 92.2 MB
    // z DEDICATED: att_soft_z reads proj (u/v rows) while writing z.
    u16* z_bf  = (u16*)alloc((size_t)N_TOT * DD * 2);          // 41.9 MB
    int* src_all  = (int*)alloc(E_TOT * 4);
    int* dst_all  = (int*)alloc(E_TOT * 4);
    int* deg      = (int*)alloc(2 * N_TOT * 4);
    int* cursor   = deg + N_TOT;
    int* edge_ids = (int*)alloc((size_t)N_TOT * CAP * 4);      // 10.2 MB padded
    (void)ws_size; (void)in_sizes; (void)n_in; (void)out_size;

    TW5 tws;
    tws.t[0] = {W_hh, Bt_h,                       Bt_h + (size_t)1024 * 1024, 1024};
    tws.t[1] = {W_oo, Bt_o,                       Bt_o + (size_t)1024 * 1024, 1024};
    tws.t[2] = {W_ho, Bt_h + (size_t)2048 * 1024, Bt_o + (size_t)2048 * 1024, 1024};
    tws.t[3] = {W_hn, Bt_hn,                      Bt_hn + 1024,               2048};
    tws.t[4] = {W_on, Bt_on,                      Bt_on + 1024,               2048};
    // 1. fused cast + edge concat + cursor zero + weight transposes
    cast_cat_tw<<<CAST_NB + CAT_NB + ZERO_NB + TW_NB, 256, 0, stream>>>(
        nf, nf_bf, shh, dhh, soo, doo, sho, dho, src_all, dst_all, cursor, tws);

    const u16* nf_bf_o = nf_bf + (size_t)N_H * DD;
    // 2. merged projections (R5-exact structure) + padded-fill tail range
    gemm_proj<<<PROJ_GEMM_NB + FILL_NB, 256, 0, stream>>>(
        nf_bf, nf_bf_o, Bt_h, Bt_o, proj_h, proj_o, dst_all, cursor, edge_ids);

    // 3. fused attention logits + online softmax + aggregation (wave-per-node)
    att_soft_z<<<N_TOT / 4, 256, 0, stream>>>(cursor, edge_ids, src_all,
                                              proj_h, proj_o, b_hh, b_oo, b_ho,
                                              W_att, b_att, nf_bf, z_bf);

    // 4. merged node apply: out = relu([nf | z] @ W + b) fp32 (XCD swizzle kept)
    gemm_node<<<(NODE_NBM_H + NODE_NBM_O) * NODE_NBN, 256, 0, stream>>>(
        nf_bf, nf_bf_o, z_bf, z_bf + (size_t)N_H * DD, Bt_hn, Bt_on,
        b_hn, b_on, out, out + (size_t)N_H * DD);
}